// Round 7
// baseline (420.507 us; speedup 1.0000x reference)
//
#include <hip/hip_runtime.h>

#define B_ 4
#define S_ 4096
#define E_ 1024
#define H_ 128
#define M_ (B_*S_)   // 16384

typedef __attribute__((ext_vector_type(8))) short bf16x8;
typedef __attribute__((ext_vector_type(4))) float f32x4;

__device__ inline ushort f2bf(float f) {
  union { float f; unsigned u; } v; v.f = f;
  unsigned r = v.u + 0x7fffu + ((v.u >> 16) & 1u);   // RNE
  return (ushort)(r >> 16);
}
__device__ inline float bf2f(ushort u) {
  union { float f; unsigned u; } v; v.u = ((unsigned)u) << 16;
  return v.f;
}
__device__ inline float bpermf(int addr, float x) {
  union { float f; int i; } v; v.f = x;
  v.i = __builtin_amdgcn_ds_bpermute(addr, v.i);
  return v.f;
}

#define GLLDS16(g, l) __builtin_amdgcn_global_load_lds( \
    (const __attribute__((address_space(1))) void*)(g), \
    (__attribute__((address_space(3))) void*)(l), 16, 0, 0)

// ---------- kernel 1: W [1024][128] f32 (x3) -> Wt [3][128][1024] bf16 ----------
__global__ __launch_bounds__(256) void wt_kernel(const float* __restrict__ Wq,
    const float* __restrict__ Wk, const float* __restrict__ Wv,
    ushort* __restrict__ Wt) {
  int bid = blockIdx.x;               // 384 = 3 mats * 4 h-tiles * 32 e-tiles
  int mat = bid >> 7;
  int rem = bid & 127;
  int ht = rem >> 5, et = rem & 31;
  const float* W = mat == 0 ? Wq : (mat == 1 ? Wk : Wv);
  int e0 = et * 32, h0 = ht * 32;
  __shared__ float tl[32][33];
  int t = threadIdx.x;
  int r = t >> 3, c = (t & 7) << 2;
  const float4 f = *(const float4*)(W + (size_t)(e0 + r) * H_ + h0 + c);
  tl[r][c] = f.x; tl[r][c+1] = f.y; tl[r][c+2] = f.z; tl[r][c+3] = f.w;
  __syncthreads();
  ushort4 o;
  o.x = f2bf(tl[c+0][r]); o.y = f2bf(tl[c+1][r]);
  o.z = f2bf(tl[c+2][r]); o.w = f2bf(tl[c+3][r]);
  *(ushort4*)(Wt + ((size_t)mat*H_ + h0 + r) * E_ + e0 + c) = o;
}

// ---------- kernel 2: x f32 -> bf16 (memory-bound) ----------
__global__ __launch_bounds__(256) void xb_kernel(const float* __restrict__ x,
                                                 ushort* __restrict__ xb) {
  size_t i = ((size_t)blockIdx.x * 256 + threadIdx.x) * 8;
  float4 f0 = *(const float4*)(x + i);
  float4 f1 = *(const float4*)(x + i + 4);
  alignas(16) ushort us[8];
  us[0]=f2bf(f0.x); us[1]=f2bf(f0.y); us[2]=f2bf(f0.z); us[3]=f2bf(f0.w);
  us[4]=f2bf(f1.x); us[5]=f2bf(f1.y); us[6]=f2bf(f1.z); us[7]=f2bf(f1.w);
  *(uint4*)(xb + i) = *(uint4*)&us[0];
}

// ---------- kernel 3: QKV GEMM, 64x128 tile, BK=64, global_load_lds, 3 blk/CU ----------
__global__ __launch_bounds__(256, 3) void qkv_gemm(const ushort* __restrict__ xb,
    const ushort* __restrict__ Wt, ushort* __restrict__ qo,
    ushort* __restrict__ ko, ushort* __restrict__ vTo) {
  const int m0 = blockIdx.x * 64;
  const int mat = blockIdx.y;
  const ushort* Bsrc = Wt + (size_t)mat * H_ * E_;
  __shared__ ushort As[2][64 * 64];
  __shared__ ushort Bs[2][128 * 64];
  const int tid = threadIdx.x;
  const int wave = tid >> 6, lane = tid & 63;
  const int col = lane & 15, quad = lane >> 4;
  const int wr = wave >> 1, wc = wave & 1;

  f32x4 acc[2][4];
  #pragma unroll
  for (int i = 0; i < 2; i++)
    #pragma unroll
    for (int j = 0; j < 4; j++) acc[i][j] = (f32x4){0.f,0.f,0.f,0.f};

  const int srow = lane >> 3;               // 0..7
  const int gcol = ((lane & 7) ^ srow) * 8; // XOR-swizzled 16B unit source offset

  #define STAGE_QKV(it, bufi) do { \
    _Pragma("unroll") \
    for (int j = 0; j < 2; j++) { \
      int rbase = wave*16 + j*8; \
      GLLDS16(xb + (size_t)(m0 + rbase + srow) * E_ + (it)*64 + gcol, \
              &As[bufi][rbase * 64]); \
    } \
    _Pragma("unroll") \
    for (int j = 0; j < 4; j++) { \
      int rbase = wave*32 + j*8; \
      GLLDS16(Bsrc + (size_t)(rbase + srow) * E_ + (it)*64 + gcol, \
              &Bs[bufi][rbase * 64]); \
    } \
  } while (0)

  STAGE_QKV(0, 0);
  __syncthreads();

  for (int it = 0; it < 16; it++) {
    if (it < 15) STAGE_QKV(it + 1, (it + 1) & 1);
    const ushort* a = &As[it & 1][0];
    const ushort* bb = &Bs[it & 1][0];
    #pragma unroll
    for (int kc = 0; kc < 2; kc++) {
      bf16x8 af[2], bf[4];
      #pragma unroll
      for (int mi = 0; mi < 2; mi++) {
        int rr = wr*32 + mi*16 + col;
        af[mi] = *(const bf16x8*)(a + rr*64 + (((kc*4 + quad) ^ (col & 7)) * 8));
      }
      #pragma unroll
      for (int ni = 0; ni < 4; ni++) {
        int rr = wc*64 + ni*16 + col;
        bf[ni] = *(const bf16x8*)(bb + rr*64 + (((kc*4 + quad) ^ (col & 7)) * 8));
      }
      #pragma unroll
      for (int mi = 0; mi < 2; mi++)
        #pragma unroll
        for (int ni = 0; ni < 4; ni++)
          acc[mi][ni] = __builtin_amdgcn_mfma_f32_16x16x32_bf16(af[mi], bf[ni], acc[mi][ni], 0, 0, 0);
    }
    __syncthreads();
  }

  if (mat == 2) {
    int bb = m0 >> 12;
    int sbase = (m0 & 4095) + wr * 32;
    #pragma unroll
    for (int ni = 0; ni < 4; ni++) {
      int n = wc*64 + ni*16 + col;
      #pragma unroll
      for (int mi = 0; mi < 2; mi++) {
        int s = sbase + mi*16 + quad*4;
        ushort4 o;
        o.x = f2bf(acc[mi][ni][0]); o.y = f2bf(acc[mi][ni][1]);
        o.z = f2bf(acc[mi][ni][2]); o.w = f2bf(acc[mi][ni][3]);
        *(ushort4*)(vTo + ((size_t)(bb * H_ + n)) * S_ + s) = o;
      }
    }
  } else {
    ushort* dst = (mat == 0 ? qo : ko);
    #pragma unroll
    for (int ni = 0; ni < 4; ni++) {
      int n = wc*64 + ni*16 + col;
      #pragma unroll
      for (int mi = 0; mi < 2; mi++) {
        int row = m0 + wr*32 + mi*16 + quad*4;
        #pragma unroll
        for (int r = 0; r < 4; r++)
          dst[(size_t)(row + r) * H_ + n] = f2bf(acc[mi][ni][r]);
      }
    }
  }
}

// ---------- kernel 4: causal flash, split-K chunk=256, tile-pair WGs, bf16 partials ----------
// grid (c=16, y=32 reversed, b=4); valid iff 2c <= tp. 1088 valid WGs.
#define CHUNK_ 256
__global__ __launch_bounds__(256, 4) void flash_kernel(const ushort* __restrict__ q,
    const ushort* __restrict__ k, const ushort* __restrict__ vT,
    ushort* __restrict__ Opart, float* __restrict__ ml) {
  const float SL2E = 0.08838834764831845f * 1.44269504088896340736f;
  int c = blockIdx.x;
  int tp = 31 - (int)blockIdx.y;              // heavy pairs first
  int b = blockIdx.z;
  if (tp < 2 * c) return;
  int tA = tp * 2, tB = tA + 1;
  int nc = (tp >> 1) + 1;
  int base2 = tp + ((tp - 1) >> 1) * (tp >> 1);   // sum of nc(t) for t<tp
  int slotA = b * 544 + 2 * base2 + c;
  int slotB = slotA + nc;

  int wave = threadIdx.x >> 6, lane = threadIdx.x & 63;
  int col = lane & 15, quad = lane >> 4;
  int xa16 = ((lane ^ 16) << 2);
  int xa32 = ((lane ^ 32) << 2);
  int q0A = tA * 64 + wave * 16;
  int q0B = q0A + 64;
  const ushort* qb = q + (size_t)b * S_ * H_;
  const ushort* kbp = k + (size_t)b * S_ * H_;
  const ushort* vb = vT + (size_t)b * H_ * S_;

  __shared__ ushort kl[2][32 * 128];          // K block, XOR-swizzled 16B units
  __shared__ ushort plds[4][2][16 * 40];      // P per (wave, tile)
  ushort* pwA = &plds[wave][0][0];
  ushort* pwB = &plds[wave][1][0];

  bf16x8 qfA[4], qfB[4];
  {
    const ushort* qpA = qb + (size_t)(q0A + col) * H_ + quad * 8;
    const ushort* qpB = qb + (size_t)(q0B + col) * H_ + quad * 8;
    #pragma unroll
    for (int kc = 0; kc < 4; kc++) {
      qfA[kc] = *(const bf16x8*)(qpA + kc * 32);
      qfB[kc] = *(const bf16x8*)(qpB + kc * 32);
    }
  }

  f32x4 OA[8], OB[8];
  #pragma unroll
  for (int d = 0; d < 8; d++) { OA[d] = (f32x4){0.f,0.f,0.f,0.f}; OB[d] = (f32x4){0.f,0.f,0.f,0.f}; }
  float mA = -1e30f, lA = 0.f, mB = -1e30f, lB = 0.f;

  const int c0 = c * CHUNK_;
  const int kendWG = min(c0 + CHUNK_, tB * 64 + 64);
  const int nblk = (kendWG - c0 + 31) >> 5;
  const int qlimA = q0A + 15, qlimB = q0B + 15;

  const int sk0 = wave * 8 + (lane >> 4);
  const int sd = lane & 15;
  const int gu0 = (sd ^ (sk0 & 15)) * 8;
  const int gu1 = (sd ^ ((sk0 + 4) & 15)) * 8;
  ushort* ld0 = &kl[0][(sk0) * 128 + sd * 8];
  ushort* ld1 = &kl[0][(sk0 + 4) * 128 + sd * 8];
  const size_t lbuf = 32 * 128;

  const ushort* vbase = vb + (size_t)col * S_ + c0 + quad * 8;

  {
    const ushort* kp = kbp + (size_t)(c0 + sk0) * H_;
    uint4 a0 = *(const uint4*)(kp + gu0);
    uint4 a1 = *(const uint4*)(kp + 4 * H_ + gu1);
    *(uint4*)ld0 = a0;
    *(uint4*)ld1 = a1;
  }
  __syncthreads();

  for (int ib = 0; ib < nblk; ib++) {
    const int kb0 = c0 + ib * 32;
    if (ib + 1 < nblk) {
      const ushort* kp = kbp + (size_t)(kb0 + 32 + sk0) * H_;
      uint4 a0 = *(const uint4*)(kp + gu0);
      uint4 a1 = *(const uint4*)(kp + 4 * H_ + gu1);
      size_t off = ((ib + 1) & 1) * lbuf;
      *(uint4*)(ld0 + off) = a0;
      *(uint4*)(ld1 + off) = a1;
    }
    if (kb0 <= qlimB) {                       // wave-uniform
      const bool doA = (kb0 <= qlimA);
      bf16x8 vf[8];
      #pragma unroll
      for (int d = 0; d < 8; d++)
        vf[d] = *(const bf16x8*)(vbase + ib * 32 + (size_t)(d * 16) * S_);
      const ushort* kcur = &kl[ib & 1][0];
      bf16x8 kf0[4], kf1[4];
      #pragma unroll
      for (int kc = 0; kc < 4; kc++) {
        int u = quad + kc * 4;
        kf0[kc] = *(const bf16x8*)(kcur + col*128        + ((u ^ (col & 15)) * 8));
        kf1[kc] = *(const bf16x8*)(kcur + (16 + col)*128 + ((u ^ (col & 15)) * 8));
      }
      f32x4 sB0 = (f32x4){0.f,0.f,0.f,0.f}, sB1 = (f32x4){0.f,0.f,0.f,0.f};
      f32x4 sA0 = (f32x4){0.f,0.f,0.f,0.f}, sA1 = (f32x4){0.f,0.f,0.f,0.f};
      #pragma unroll
      for (int kc = 0; kc < 4; kc++) {
        sB0 = __builtin_amdgcn_mfma_f32_16x16x32_bf16(kf0[kc], qfB[kc], sB0, 0, 0, 0);
        sB1 = __builtin_amdgcn_mfma_f32_16x16x32_bf16(kf1[kc], qfB[kc], sB1, 0, 0, 0);
      }
      if (doA) {
        #pragma unroll
        for (int kc = 0; kc < 4; kc++) {
          sA0 = __builtin_amdgcn_mfma_f32_16x16x32_bf16(kf0[kc], qfA[kc], sA0, 0, 0, 0);
          sA1 = __builtin_amdgcn_mfma_f32_16x16x32_bf16(kf1[kc], qfA[kc], sA1, 0, 0, 0);
        }
      }
      // ---- tile B softmax ----
      {
        float s[8];
        #pragma unroll
        for (int r = 0; r < 4; r++) { s[r] = sB0[r]; s[4+r] = sB1[r]; }
        if (kb0 + 31 > q0B) {
          #pragma unroll
          for (int r = 0; r < 4; r++) {
            if (kb0 + quad*4 + r      > q0B + col) s[r]   = -1e30f;
            if (kb0 + 16 + quad*4 + r > q0B + col) s[4+r] = -1e30f;
          }
        }
        float cm = s[0];
        #pragma unroll
        for (int j = 1; j < 8; j++) cm = fmaxf(cm, s[j]);
        cm = fmaxf(cm, bpermf(xa16, cm));
        cm = fmaxf(cm, bpermf(xa32, cm));
        float mn = fmaxf(mB, cm);
        float alpha = exp2f((mB - mn) * SL2E);
        mB = mn;
        float p[8], rs = 0.f;
        #pragma unroll
        for (int j = 0; j < 8; j++) { p[j] = exp2f((s[j] - mn) * SL2E); rs += p[j]; }
        rs += bpermf(xa16, rs);
        rs += bpermf(xa32, rs);
        lB = lB * alpha + rs;
        #pragma unroll
        for (int d = 0; d < 8; d++) OB[d] *= alpha;
        unsigned* pq = (unsigned*)(pwB + col * 40);
        pq[quad*2]     = (unsigned)f2bf(p[0]) | ((unsigned)f2bf(p[1]) << 16);
        pq[quad*2+1]   = (unsigned)f2bf(p[2]) | ((unsigned)f2bf(p[3]) << 16);
        pq[8+quad*2]   = (unsigned)f2bf(p[4]) | ((unsigned)f2bf(p[5]) << 16);
        pq[8+quad*2+1] = (unsigned)f2bf(p[6]) | ((unsigned)f2bf(p[7]) << 16);
      }
      // ---- tile A softmax ----
      if (doA) {
        float s[8];
        #pragma unroll
        for (int r = 0; r < 4; r++) { s[r] = sA0[r]; s[4+r] = sA1[r]; }
        if (kb0 + 31 > q0A) {
          #pragma unroll
          for (int r = 0; r < 4; r++) {
            if (kb0 + quad*4 + r      > q0A + col) s[r]   = -1e30f;
            if (kb0 + 16 + quad*4 + r > q0A + col) s[4+r] = -1e30f;
          }
        }
        float cm = s[0];
        #pragma unroll
        for (int j = 1; j < 8; j++) cm = fmaxf(cm, s[j]);
        cm = fmaxf(cm, bpermf(xa16, cm));
        cm = fmaxf(cm, bpermf(xa32, cm));
        float mn = fmaxf(mA, cm);
        float alpha = exp2f((mA - mn) * SL2E);
        mA = mn;
        float p[8], rs = 0.f;
        #pragma unroll
        for (int j = 0; j < 8; j++) { p[j] = exp2f((s[j] - mn) * SL2E); rs += p[j]; }
        rs += bpermf(xa16, rs);
        rs += bpermf(xa32, rs);
        lA = lA * alpha + rs;
        #pragma unroll
        for (int d = 0; d < 8; d++) OA[d] *= alpha;
        unsigned* pq = (unsigned*)(pwA + col * 40);
        pq[quad*2]     = (unsigned)f2bf(p[0]) | ((unsigned)f2bf(p[1]) << 16);
        pq[quad*2+1]   = (unsigned)f2bf(p[2]) | ((unsigned)f2bf(p[3]) << 16);
        pq[8+quad*2]   = (unsigned)f2bf(p[4]) | ((unsigned)f2bf(p[5]) << 16);
        pq[8+quad*2+1] = (unsigned)f2bf(p[6]) | ((unsigned)f2bf(p[7]) << 16);
      }
      // ---- PV for both ----
      {
        bf16x8 pfB = *(const bf16x8*)(pwB + col * 40 + quad * 8);
        #pragma unroll
        for (int d = 0; d < 8; d++)
          OB[d] = __builtin_amdgcn_mfma_f32_16x16x32_bf16(vf[d], pfB, OB[d], 0, 0, 0);
        if (doA) {
          bf16x8 pfA = *(const bf16x8*)(pwA + col * 40 + quad * 8);
          #pragma unroll
          for (int d = 0; d < 8; d++)
            OA[d] = __builtin_amdgcn_mfma_f32_16x16x32_bf16(vf[d], pfA, OA[d], 0, 0, 0);
        }
      }
    }
    __syncthreads();
  }

  // bf16 partials
  ushort* OpA = Opart + (size_t)slotA * 8192 + (size_t)(wave*16 + col) * 128 + quad * 4;
  ushort* OpB = Opart + (size_t)slotB * 8192 + (size_t)(wave*16 + col) * 128 + quad * 4;
  #pragma unroll
  for (int d = 0; d < 8; d++) {
    ushort4 oa, ob;
    oa.x=f2bf(OA[d][0]); oa.y=f2bf(OA[d][1]); oa.z=f2bf(OA[d][2]); oa.w=f2bf(OA[d][3]);
    ob.x=f2bf(OB[d][0]); ob.y=f2bf(OB[d][1]); ob.z=f2bf(OB[d][2]); ob.w=f2bf(OB[d][3]);
    *(ushort4*)(OpA + d * 16) = oa;
    *(ushort4*)(OpB + d * 16) = ob;
  }
  if (quad == 0) {
    *(float2*)(ml + (size_t)slotA * 128 + (size_t)(wave*16 + col) * 2) = make_float2(mA, lA);
    *(float2*)(ml + (size_t)slotB * 128 + (size_t)(wave*16 + col) * 2) = make_float2(mB, lB);
  }
}

// ---------- kernel 5: combine split-K partials (bf16 partials, <=16 chunks) ----------
__global__ __launch_bounds__(256) void combine_kernel(const ushort* __restrict__ Opart,
    const float* __restrict__ ml, float* __restrict__ out) {
  const float SL2E = 0.08838834764831845f * 1.44269504088896340736f;
  int tile = blockIdx.x, b = blockIdx.y;
  int tp = tile >> 1;
  int nc = (tp >> 1) + 1;
  int base2 = tp + ((tp - 1) >> 1) * (tp >> 1);
  int base = b * 544 + 2 * base2 + (tile & 1) * nc;
  int tid = threadIdx.x;
  int row = tid >> 2;
  int cs = (tid & 3) * 4;
  float m_c[16], l_c[16], w_c[16];
  float mstar = -1e30f;
  for (int ci = 0; ci < nc; ci++) {
    m_c[ci] = ml[(size_t)(base + ci) * 128 + row * 2];
    l_c[ci] = ml[(size_t)(base + ci) * 128 + row * 2 + 1];
    mstar = fmaxf(mstar, m_c[ci]);
  }
  float denom = 0.f;
  for (int ci = 0; ci < nc; ci++) {
    w_c[ci] = exp2f((m_c[ci] - mstar) * SL2E);
    denom += w_c[ci] * l_c[ci];
  }
  float inv = 1.f / denom;
  f32x4 acc[8];
  #pragma unroll
  for (int i = 0; i < 8; i++) acc[i] = (f32x4){0.f,0.f,0.f,0.f};
  for (int ci = 0; ci < nc; ci++) {
    const ushort* Op = Opart + (size_t)(base + ci) * 8192 + row * 128;
    float w = w_c[ci];
    #pragma unroll
    for (int i = 0; i < 8; i++) {
      ushort4 u = *(const ushort4*)(Op + cs + i * 16);
      acc[i][0] += w * bf2f(u.x);
      acc[i][1] += w * bf2f(u.y);
      acc[i][2] += w * bf2f(u.z);
      acc[i][3] += w * bf2f(u.w);
    }
  }
  float* o = out + ((size_t)(b * S_) + tile * 64 + row) * H_;
  #pragma unroll
  for (int i = 0; i < 8; i++) {
    f32x4 v = acc[i] * inv;
    *(f32x4*)(o + cs + i * 16) = v;
  }
}

extern "C" void kernel_launch(void* const* d_in, const int* in_sizes, int n_in,
                              void* d_out, int out_size, void* d_ws, size_t ws_size,
                              hipStream_t stream) {
  (void)in_sizes; (void)n_in; (void)out_size; (void)ws_size;
  const float* x  = (const float*)d_in[0];
  const float* Wq = (const float*)d_in[1];
  const float* Wk = (const float*)d_in[2];
  const float* Wv = (const float*)d_in[3];
  float* out = (float*)d_out;
  char* ws = (char*)d_ws;
  ushort* Wt = (ushort*)ws;                                        // 768 KB
  ushort* qb = (ushort*)(ws + 786432);                             // 4 MB each
  ushort* kb = qb + (size_t)M_ * H_;
  ushort* vT = kb + (size_t)M_ * H_;
  ushort* Opart = (ushort*)(ws + 786432 + 3 * (size_t)M_ * H_ * 2); // 2176*16KB = 35.7MB
  float* ml = (float*)(Opart + (size_t)2176 * 8192);               // 2176*512B
  ushort* xbuf = Opart;            // alias: xbuf dead before flash writes Opart

  hipLaunchKernelGGL(wt_kernel,   dim3(384), dim3(256), 0, stream, Wq, Wk, Wv, Wt);
  hipLaunchKernelGGL(xb_kernel,   dim3(8192), dim3(256), 0, stream, x, xbuf);
  hipLaunchKernelGGL(qkv_gemm,    dim3(256, 3), dim3(256), 0, stream, xbuf, Wt, qb, kb, vT);
  hipLaunchKernelGGL(flash_kernel,dim3(16, 32, 4), dim3(256), 0, stream, qb, kb, vT, Opart, ml);
  hipLaunchKernelGGL(combine_kernel, dim3(64, 4), dim3(256), 0, stream, Opart, ml, out);
}

// Round 8
// 321.156 us; speedup vs baseline: 1.3094x; 1.3094x over previous
//
#include <hip/hip_runtime.h>

#define B_ 4
#define S_ 4096
#define E_ 1024
#define H_ 128
#define M_ (B_*S_)   // 16384

typedef __attribute__((ext_vector_type(8))) short bf16x8;
typedef __attribute__((ext_vector_type(4))) float f32x4;

__device__ inline ushort f2bf(float f) {
  union { float f; unsigned u; } v; v.f = f;
  unsigned r = v.u + 0x7fffu + ((v.u >> 16) & 1u);   // RNE
  return (ushort)(r >> 16);
}
__device__ inline float bf2f(ushort u) {
  union { float f; unsigned u; } v; v.u = ((unsigned)u) << 16;
  return v.f;
}
__device__ inline float bpermf(int addr, float x) {
  union { float f; int i; } v; v.f = x;
  v.i = __builtin_amdgcn_ds_bpermute(addr, v.i);
  return v.f;
}

#define GLLDS16(g, l) __builtin_amdgcn_global_load_lds( \
    (const __attribute__((address_space(1))) void*)(g), \
    (__attribute__((address_space(3))) void*)(l), 16, 0, 0)

// ---------- kernel 1: W [1024][128] f32 (x3) -> Wt [3][128][1024] bf16 ----------
__global__ __launch_bounds__(256) void wt_kernel(const float* __restrict__ Wq,
    const float* __restrict__ Wk, const float* __restrict__ Wv,
    ushort* __restrict__ Wt) {
  int bid = blockIdx.x;               // 384 = 3 mats * 4 h-tiles * 32 e-tiles
  int mat = bid >> 7;
  int rem = bid & 127;
  int ht = rem >> 5, et = rem & 31;
  const float* W = mat == 0 ? Wq : (mat == 1 ? Wk : Wv);
  int e0 = et * 32, h0 = ht * 32;
  __shared__ float tl[32][33];
  int t = threadIdx.x;
  int r = t >> 3, c = (t & 7) << 2;
  const float4 f = *(const float4*)(W + (size_t)(e0 + r) * H_ + h0 + c);
  tl[r][c] = f.x; tl[r][c+1] = f.y; tl[r][c+2] = f.z; tl[r][c+3] = f.w;
  __syncthreads();
  ushort4 o;
  o.x = f2bf(tl[c+0][r]); o.y = f2bf(tl[c+1][r]);
  o.z = f2bf(tl[c+2][r]); o.w = f2bf(tl[c+3][r]);
  *(ushort4*)(Wt + ((size_t)mat*H_ + h0 + r) * E_ + e0 + c) = o;
}

// ---------- kernel 2: x f32 -> bf16 (memory-bound) ----------
__global__ __launch_bounds__(256) void xb_kernel(const float* __restrict__ x,
                                                 ushort* __restrict__ xb) {
  size_t i = ((size_t)blockIdx.x * 256 + threadIdx.x) * 8;
  float4 f0 = *(const float4*)(x + i);
  float4 f1 = *(const float4*)(x + i + 4);
  alignas(16) ushort us[8];
  us[0]=f2bf(f0.x); us[1]=f2bf(f0.y); us[2]=f2bf(f0.z); us[3]=f2bf(f0.w);
  us[4]=f2bf(f1.x); us[5]=f2bf(f1.y); us[6]=f2bf(f1.z); us[7]=f2bf(f1.w);
  *(uint4*)(xb + i) = *(uint4*)&us[0];
}

// ---------- kernel 3: QKV GEMM, 64x128 tile, BK=64, global_load_lds, 3 blk/CU ----------
__global__ __launch_bounds__(256, 3) void qkv_gemm(const ushort* __restrict__ xb,
    const ushort* __restrict__ Wt, ushort* __restrict__ qo,
    ushort* __restrict__ ko, ushort* __restrict__ vTo) {
  const int m0 = blockIdx.x * 64;
  const int mat = blockIdx.y;
  const ushort* Bsrc = Wt + (size_t)mat * H_ * E_;
  __shared__ ushort As[2][64 * 64];
  __shared__ ushort Bs[2][128 * 64];
  const int tid = threadIdx.x;
  const int wave = tid >> 6, lane = tid & 63;
  const int col = lane & 15, quad = lane >> 4;
  const int wr = wave >> 1, wc = wave & 1;

  f32x4 acc[2][4];
  #pragma unroll
  for (int i = 0; i < 2; i++)
    #pragma unroll
    for (int j = 0; j < 4; j++) acc[i][j] = (f32x4){0.f,0.f,0.f,0.f};

  const int srow = lane >> 3;               // 0..7
  const int gcol = ((lane & 7) ^ srow) * 8; // XOR-swizzled 16B unit source offset

  #define STAGE_QKV(it, bufi) do { \
    _Pragma("unroll") \
    for (int j = 0; j < 2; j++) { \
      int rbase = wave*16 + j*8; \
      GLLDS16(xb + (size_t)(m0 + rbase + srow) * E_ + (it)*64 + gcol, \
              &As[bufi][rbase * 64]); \
    } \
    _Pragma("unroll") \
    for (int j = 0; j < 4; j++) { \
      int rbase = wave*32 + j*8; \
      GLLDS16(Bsrc + (size_t)(rbase + srow) * E_ + (it)*64 + gcol, \
              &Bs[bufi][rbase * 64]); \
    } \
  } while (0)

  STAGE_QKV(0, 0);
  __syncthreads();

  for (int it = 0; it < 16; it++) {
    if (it < 15) STAGE_QKV(it + 1, (it + 1) & 1);
    const ushort* a = &As[it & 1][0];
    const ushort* bb = &Bs[it & 1][0];
    #pragma unroll
    for (int kc = 0; kc < 2; kc++) {
      bf16x8 af[2], bf[4];
      #pragma unroll
      for (int mi = 0; mi < 2; mi++) {
        int rr = wr*32 + mi*16 + col;
        af[mi] = *(const bf16x8*)(a + rr*64 + (((kc*4 + quad) ^ (col & 7)) * 8));
      }
      #pragma unroll
      for (int ni = 0; ni < 4; ni++) {
        int rr = wc*64 + ni*16 + col;
        bf[ni] = *(const bf16x8*)(bb + rr*64 + (((kc*4 + quad) ^ (col & 7)) * 8));
      }
      #pragma unroll
      for (int mi = 0; mi < 2; mi++)
        #pragma unroll
        for (int ni = 0; ni < 4; ni++)
          acc[mi][ni] = __builtin_amdgcn_mfma_f32_16x16x32_bf16(af[mi], bf[ni], acc[mi][ni], 0, 0, 0);
    }
    __syncthreads();
  }

  if (mat == 2) {
    int bb = m0 >> 12;
    int sbase = (m0 & 4095) + wr * 32;
    #pragma unroll
    for (int ni = 0; ni < 4; ni++) {
      int n = wc*64 + ni*16 + col;
      #pragma unroll
      for (int mi = 0; mi < 2; mi++) {
        int s = sbase + mi*16 + quad*4;
        ushort4 o;
        o.x = f2bf(acc[mi][ni][0]); o.y = f2bf(acc[mi][ni][1]);
        o.z = f2bf(acc[mi][ni][2]); o.w = f2bf(acc[mi][ni][3]);
        *(ushort4*)(vTo + ((size_t)(bb * H_ + n)) * S_ + s) = o;
      }
    }
  } else {
    ushort* dst = (mat == 0 ? qo : ko);
    #pragma unroll
    for (int ni = 0; ni < 4; ni++) {
      int n = wc*64 + ni*16 + col;
      #pragma unroll
      for (int mi = 0; mi < 2; mi++) {
        int row = m0 + wr*32 + mi*16 + quad*4;
        #pragma unroll
        for (int r = 0; r < 4; r++)
          dst[(size_t)(row + r) * H_ + n] = f2bf(acc[mi][ni][r]);
      }
    }
  }
}

// ---------- kernel 4: causal flash, split-K chunk=256, tile-pair WGs, bf16 partials ----------
// grid (c=16, y=32 reversed, b=4); valid iff 2c <= tp. 1088 valid WGs.
// NOTE: launch_bounds min-waves MUST stay <=3: (256,4) forces VGPR=64 -> ~600MB
// scratch spill (R7: 283us, WRITE_SIZE 345MB). RA needs ~110-160 regs here.
#define CHUNK_ 256
__global__ __launch_bounds__(256, 3) void flash_kernel(const ushort* __restrict__ q,
    const ushort* __restrict__ k, const ushort* __restrict__ vT,
    ushort* __restrict__ Opart, float* __restrict__ ml) {
  const float SL2E = 0.08838834764831845f * 1.44269504088896340736f;
  int c = blockIdx.x;
  int tp = 31 - (int)blockIdx.y;              // heavy pairs first
  int b = blockIdx.z;
  if (tp < 2 * c) return;
  int tA = tp * 2, tB = tA + 1;
  int nc = (tp >> 1) + 1;
  int base2 = tp + ((tp - 1) >> 1) * (tp >> 1);   // sum of nc(t) for t<tp
  int slotA = b * 544 + 2 * base2 + c;
  int slotB = slotA + nc;

  int wave = threadIdx.x >> 6, lane = threadIdx.x & 63;
  int col = lane & 15, quad = lane >> 4;
  int xa16 = ((lane ^ 16) << 2);
  int xa32 = ((lane ^ 32) << 2);
  int q0A = tA * 64 + wave * 16;
  int q0B = q0A + 64;
  const ushort* qb = q + (size_t)b * S_ * H_;
  const ushort* kbp = k + (size_t)b * S_ * H_;
  const ushort* vb = vT + (size_t)b * H_ * S_;

  __shared__ ushort kl[2][32 * 128];          // K block, XOR-swizzled 16B units
  __shared__ ushort plds[4][2][16 * 40];      // P per (wave, tile)
  ushort* pwA = &plds[wave][0][0];
  ushort* pwB = &plds[wave][1][0];

  bf16x8 qfA[4], qfB[4];
  {
    const ushort* qpA = qb + (size_t)(q0A + col) * H_ + quad * 8;
    const ushort* qpB = qb + (size_t)(q0B + col) * H_ + quad * 8;
    #pragma unroll
    for (int kc = 0; kc < 4; kc++) {
      qfA[kc] = *(const bf16x8*)(qpA + kc * 32);
      qfB[kc] = *(const bf16x8*)(qpB + kc * 32);
    }
  }

  f32x4 OA[8], OB[8];
  #pragma unroll
  for (int d = 0; d < 8; d++) { OA[d] = (f32x4){0.f,0.f,0.f,0.f}; OB[d] = (f32x4){0.f,0.f,0.f,0.f}; }
  float mA = -1e30f, lA = 0.f, mB = -1e30f, lB = 0.f;

  const int c0 = c * CHUNK_;
  const int kendWG = min(c0 + CHUNK_, tB * 64 + 64);
  const int nblk = (kendWG - c0 + 31) >> 5;
  const int qlimA = q0A + 15, qlimB = q0B + 15;

  const int sk0 = wave * 8 + (lane >> 4);
  const int sd = lane & 15;
  const int gu0 = (sd ^ (sk0 & 15)) * 8;
  const int gu1 = (sd ^ ((sk0 + 4) & 15)) * 8;
  ushort* ld0 = &kl[0][(sk0) * 128 + sd * 8];
  ushort* ld1 = &kl[0][(sk0 + 4) * 128 + sd * 8];
  const size_t lbuf = 32 * 128;

  const ushort* vbase = vb + (size_t)col * S_ + c0 + quad * 8;

  {
    const ushort* kp = kbp + (size_t)(c0 + sk0) * H_;
    uint4 a0 = *(const uint4*)(kp + gu0);
    uint4 a1 = *(const uint4*)(kp + 4 * H_ + gu1);
    *(uint4*)ld0 = a0;
    *(uint4*)ld1 = a1;
  }
  __syncthreads();

  for (int ib = 0; ib < nblk; ib++) {
    const int kb0 = c0 + ib * 32;
    if (ib + 1 < nblk) {
      const ushort* kp = kbp + (size_t)(kb0 + 32 + sk0) * H_;
      uint4 a0 = *(const uint4*)(kp + gu0);
      uint4 a1 = *(const uint4*)(kp + 4 * H_ + gu1);
      size_t off = ((ib + 1) & 1) * lbuf;
      *(uint4*)(ld0 + off) = a0;
      *(uint4*)(ld1 + off) = a1;
    }
    if (kb0 <= qlimB) {                       // wave-uniform
      const bool doA = (kb0 <= qlimA);
      bf16x8 vf[8];
      #pragma unroll
      for (int d = 0; d < 8; d++)
        vf[d] = *(const bf16x8*)(vbase + ib * 32 + (size_t)(d * 16) * S_);
      const ushort* kcur = &kl[ib & 1][0];
      bf16x8 kf0[4], kf1[4];
      #pragma unroll
      for (int kc = 0; kc < 4; kc++) {
        int u = quad + kc * 4;
        kf0[kc] = *(const bf16x8*)(kcur + col*128        + ((u ^ (col & 15)) * 8));
        kf1[kc] = *(const bf16x8*)(kcur + (16 + col)*128 + ((u ^ (col & 15)) * 8));
      }
      f32x4 sB0 = (f32x4){0.f,0.f,0.f,0.f}, sB1 = (f32x4){0.f,0.f,0.f,0.f};
      f32x4 sA0 = (f32x4){0.f,0.f,0.f,0.f}, sA1 = (f32x4){0.f,0.f,0.f,0.f};
      #pragma unroll
      for (int kc = 0; kc < 4; kc++) {
        sB0 = __builtin_amdgcn_mfma_f32_16x16x32_bf16(kf0[kc], qfB[kc], sB0, 0, 0, 0);
        sB1 = __builtin_amdgcn_mfma_f32_16x16x32_bf16(kf1[kc], qfB[kc], sB1, 0, 0, 0);
      }
      if (doA) {
        #pragma unroll
        for (int kc = 0; kc < 4; kc++) {
          sA0 = __builtin_amdgcn_mfma_f32_16x16x32_bf16(kf0[kc], qfA[kc], sA0, 0, 0, 0);
          sA1 = __builtin_amdgcn_mfma_f32_16x16x32_bf16(kf1[kc], qfA[kc], sA1, 0, 0, 0);
        }
      }
      // ---- tile B softmax ----
      {
        float s[8];
        #pragma unroll
        for (int r = 0; r < 4; r++) { s[r] = sB0[r]; s[4+r] = sB1[r]; }
        if (kb0 + 31 > q0B) {
          #pragma unroll
          for (int r = 0; r < 4; r++) {
            if (kb0 + quad*4 + r      > q0B + col) s[r]   = -1e30f;
            if (kb0 + 16 + quad*4 + r > q0B + col) s[4+r] = -1e30f;
          }
        }
        float cm = s[0];
        #pragma unroll
        for (int j = 1; j < 8; j++) cm = fmaxf(cm, s[j]);
        cm = fmaxf(cm, bpermf(xa16, cm));
        cm = fmaxf(cm, bpermf(xa32, cm));
        float mn = fmaxf(mB, cm);
        float alpha = exp2f((mB - mn) * SL2E);
        mB = mn;
        float p[8], rs = 0.f;
        #pragma unroll
        for (int j = 0; j < 8; j++) { p[j] = exp2f((s[j] - mn) * SL2E); rs += p[j]; }
        rs += bpermf(xa16, rs);
        rs += bpermf(xa32, rs);
        lB = lB * alpha + rs;
        #pragma unroll
        for (int d = 0; d < 8; d++) OB[d] *= alpha;
        unsigned* pq = (unsigned*)(pwB + col * 40);
        pq[quad*2]     = (unsigned)f2bf(p[0]) | ((unsigned)f2bf(p[1]) << 16);
        pq[quad*2+1]   = (unsigned)f2bf(p[2]) | ((unsigned)f2bf(p[3]) << 16);
        pq[8+quad*2]   = (unsigned)f2bf(p[4]) | ((unsigned)f2bf(p[5]) << 16);
        pq[8+quad*2+1] = (unsigned)f2bf(p[6]) | ((unsigned)f2bf(p[7]) << 16);
      }
      // ---- tile A softmax ----
      if (doA) {
        float s[8];
        #pragma unroll
        for (int r = 0; r < 4; r++) { s[r] = sA0[r]; s[4+r] = sA1[r]; }
        if (kb0 + 31 > q0A) {
          #pragma unroll
          for (int r = 0; r < 4; r++) {
            if (kb0 + quad*4 + r      > q0A + col) s[r]   = -1e30f;
            if (kb0 + 16 + quad*4 + r > q0A + col) s[4+r] = -1e30f;
          }
        }
        float cm = s[0];
        #pragma unroll
        for (int j = 1; j < 8; j++) cm = fmaxf(cm, s[j]);
        cm = fmaxf(cm, bpermf(xa16, cm));
        cm = fmaxf(cm, bpermf(xa32, cm));
        float mn = fmaxf(mA, cm);
        float alpha = exp2f((mA - mn) * SL2E);
        mA = mn;
        float p[8], rs = 0.f;
        #pragma unroll
        for (int j = 0; j < 8; j++) { p[j] = exp2f((s[j] - mn) * SL2E); rs += p[j]; }
        rs += bpermf(xa16, rs);
        rs += bpermf(xa32, rs);
        lA = lA * alpha + rs;
        #pragma unroll
        for (int d = 0; d < 8; d++) OA[d] *= alpha;
        unsigned* pq = (unsigned*)(pwA + col * 40);
        pq[quad*2]     = (unsigned)f2bf(p[0]) | ((unsigned)f2bf(p[1]) << 16);
        pq[quad*2+1]   = (unsigned)f2bf(p[2]) | ((unsigned)f2bf(p[3]) << 16);
        pq[8+quad*2]   = (unsigned)f2bf(p[4]) | ((unsigned)f2bf(p[5]) << 16);
        pq[8+quad*2+1] = (unsigned)f2bf(p[6]) | ((unsigned)f2bf(p[7]) << 16);
      }
      // ---- PV for both ----
      {
        bf16x8 pfB = *(const bf16x8*)(pwB + col * 40 + quad * 8);
        #pragma unroll
        for (int d = 0; d < 8; d++)
          OB[d] = __builtin_amdgcn_mfma_f32_16x16x32_bf16(vf[d], pfB, OB[d], 0, 0, 0);
        if (doA) {
          bf16x8 pfA = *(const bf16x8*)(pwA + col * 40 + quad * 8);
          #pragma unroll
          for (int d = 0; d < 8; d++)
            OA[d] = __builtin_amdgcn_mfma_f32_16x16x32_bf16(vf[d], pfA, OA[d], 0, 0, 0);
        }
      }
    }
    __syncthreads();
  }

  // bf16 partials
  ushort* OpA = Opart + (size_t)slotA * 8192 + (size_t)(wave*16 + col) * 128 + quad * 4;
  ushort* OpB = Opart + (size_t)slotB * 8192 + (size_t)(wave*16 + col) * 128 + quad * 4;
  #pragma unroll
  for (int d = 0; d < 8; d++) {
    ushort4 oa, ob;
    oa.x=f2bf(OA[d][0]); oa.y=f2bf(OA[d][1]); oa.z=f2bf(OA[d][2]); oa.w=f2bf(OA[d][3]);
    ob.x=f2bf(OB[d][0]); ob.y=f2bf(OB[d][1]); ob.z=f2bf(OB[d][2]); ob.w=f2bf(OB[d][3]);
    *(ushort4*)(OpA + d * 16) = oa;
    *(ushort4*)(OpB + d * 16) = ob;
  }
  if (quad == 0) {
    *(float2*)(ml + (size_t)slotA * 128 + (size_t)(wave*16 + col) * 2) = make_float2(mA, lA);
    *(float2*)(ml + (size_t)slotB * 128 + (size_t)(wave*16 + col) * 2) = make_float2(mB, lB);
  }
}

// ---------- kernel 5: combine split-K partials (bf16 partials, <=16 chunks) ----------
__global__ __launch_bounds__(256) void combine_kernel(const ushort* __restrict__ Opart,
    const float* __restrict__ ml, float* __restrict__ out) {
  const float SL2E = 0.08838834764831845f * 1.44269504088896340736f;
  int tile = blockIdx.x, b = blockIdx.y;
  int tp = tile >> 1;
  int nc = (tp >> 1) + 1;
  int base2 = tp + ((tp - 1) >> 1) * (tp >> 1);
  int base = b * 544 + 2 * base2 + (tile & 1) * nc;
  int tid = threadIdx.x;
  int row = tid >> 2;
  int cs = (tid & 3) * 4;
  float m_c[16], l_c[16], w_c[16];
  float mstar = -1e30f;
  for (int ci = 0; ci < nc; ci++) {
    m_c[ci] = ml[(size_t)(base + ci) * 128 + row * 2];
    l_c[ci] = ml[(size_t)(base + ci) * 128 + row * 2 + 1];
    mstar = fmaxf(mstar, m_c[ci]);
  }
  float denom = 0.f;
  for (int ci = 0; ci < nc; ci++) {
    w_c[ci] = exp2f((m_c[ci] - mstar) * SL2E);
    denom += w_c[ci] * l_c[ci];
  }
  float inv = 1.f / denom;
  f32x4 acc[8];
  #pragma unroll
  for (int i = 0; i < 8; i++) acc[i] = (f32x4){0.f,0.f,0.f,0.f};
  for (int ci = 0; ci < nc; ci++) {
    const ushort* Op = Opart + (size_t)(base + ci) * 8192 + row * 128;
    float w = w_c[ci];
    #pragma unroll
    for (int i = 0; i < 8; i++) {
      ushort4 u = *(const ushort4*)(Op + cs + i * 16);
      acc[i][0] += w * bf2f(u.x);
      acc[i][1] += w * bf2f(u.y);
      acc[i][2] += w * bf2f(u.z);
      acc[i][3] += w * bf2f(u.w);
    }
  }
  float* o = out + ((size_t)(b * S_) + tile * 64 + row) * H_;
  #pragma unroll
  for (int i = 0; i < 8; i++) {
    f32x4 v = acc[i] * inv;
    *(f32x4*)(o + cs + i * 16) = v;
  }
}

extern "C" void kernel_launch(void* const* d_in, const int* in_sizes, int n_in,
                              void* d_out, int out_size, void* d_ws, size_t ws_size,
                              hipStream_t stream) {
  (void)in_sizes; (void)n_in; (void)out_size; (void)ws_size;
  const float* x  = (const float*)d_in[0];
  const float* Wq = (const float*)d_in[1];
  const float* Wk = (const float*)d_in[2];
  const float* Wv = (const float*)d_in[3];
  float* out = (float*)d_out;
  char* ws = (char*)d_ws;
  ushort* Wt = (ushort*)ws;                                        // 768 KB
  ushort* qb = (ushort*)(ws + 786432);                             // 4 MB each
  ushort* kb = qb + (size_t)M_ * H_;
  ushort* vT = kb + (size_t)M_ * H_;
  ushort* Opart = (ushort*)(ws + 786432 + 3 * (size_t)M_ * H_ * 2); // 2176*16KB = 35.7MB
  float* ml = (float*)(Opart + (size_t)2176 * 8192);               // 2176*512B
  ushort* xbuf = Opart;            // alias: xbuf dead before flash writes Opart

  hipLaunchKernelGGL(wt_kernel,   dim3(384), dim3(256), 0, stream, Wq, Wk, Wv, Wt);
  hipLaunchKernelGGL(xb_kernel,   dim3(8192), dim3(256), 0, stream, x, xbuf);
  hipLaunchKernelGGL(qkv_gemm,    dim3(256, 3), dim3(256), 0, stream, xbuf, Wt, qb, kb, vT);
  hipLaunchKernelGGL(flash_kernel,dim3(16, 32, 4), dim3(256), 0, stream, qb, kb, vT, Opart, ml);
  hipLaunchKernelGGL(combine_kernel, dim3(64, 4), dim3(256), 0, stream, Opart, ml, out);
}

// Round 9
// 245.513 us; speedup vs baseline: 1.7128x; 1.3081x over previous
//
#include <hip/hip_runtime.h>

#define B_ 4
#define S_ 4096
#define E_ 1024
#define H_ 128
#define M_ (B_*S_)   // 16384

typedef __attribute__((ext_vector_type(8))) short bf16x8;
typedef __attribute__((ext_vector_type(4))) float f32x4;

__device__ inline ushort f2bf(float f) {
  union { float f; unsigned u; } v; v.f = f;
  unsigned r = v.u + 0x7fffu + ((v.u >> 16) & 1u);   // RNE
  return (ushort)(r >> 16);
}
__device__ inline float bf2f(ushort u) {
  union { float f; unsigned u; } v; v.u = ((unsigned)u) << 16;
  return v.f;
}
__device__ inline float bpermf(int addr, float x) {
  union { float f; int i; } v; v.f = x;
  v.i = __builtin_amdgcn_ds_bpermute(addr, v.i);
  return v.f;
}

#define GLLDS16(g, l) __builtin_amdgcn_global_load_lds( \
    (const __attribute__((address_space(1))) void*)(g), \
    (__attribute__((address_space(3))) void*)(l), 16, 0, 0)

// ---------- kernel 1: W [1024][128] f32 (x3) -> Wt [3][128][1024] bf16 ----------
__global__ __launch_bounds__(256) void wt_kernel(const float* __restrict__ Wq,
    const float* __restrict__ Wk, const float* __restrict__ Wv,
    ushort* __restrict__ Wt) {
  int bid = blockIdx.x;               // 384 = 3 mats * 4 h-tiles * 32 e-tiles
  int mat = bid >> 7;
  int rem = bid & 127;
  int ht = rem >> 5, et = rem & 31;
  const float* W = mat == 0 ? Wq : (mat == 1 ? Wk : Wv);
  int e0 = et * 32, h0 = ht * 32;
  __shared__ float tl[32][33];
  int t = threadIdx.x;
  int r = t >> 3, c = (t & 7) << 2;
  const float4 f = *(const float4*)(W + (size_t)(e0 + r) * H_ + h0 + c);
  tl[r][c] = f.x; tl[r][c+1] = f.y; tl[r][c+2] = f.z; tl[r][c+3] = f.w;
  __syncthreads();
  ushort4 o;
  o.x = f2bf(tl[c+0][r]); o.y = f2bf(tl[c+1][r]);
  o.z = f2bf(tl[c+2][r]); o.w = f2bf(tl[c+3][r]);
  *(ushort4*)(Wt + ((size_t)mat*H_ + h0 + r) * E_ + e0 + c) = o;
}

// ---------- kernel 2: x f32 -> bf16 (memory-bound) ----------
__global__ __launch_bounds__(256) void xb_kernel(const float* __restrict__ x,
                                                 ushort* __restrict__ xb) {
  size_t i = ((size_t)blockIdx.x * 256 + threadIdx.x) * 8;
  float4 f0 = *(const float4*)(x + i);
  float4 f1 = *(const float4*)(x + i + 4);
  alignas(16) ushort us[8];
  us[0]=f2bf(f0.x); us[1]=f2bf(f0.y); us[2]=f2bf(f0.z); us[3]=f2bf(f0.w);
  us[4]=f2bf(f1.x); us[5]=f2bf(f1.y); us[6]=f2bf(f1.z); us[7]=f2bf(f1.w);
  *(uint4*)(xb + i) = *(uint4*)&us[0];
}

// ---------- kernel 3: QKV GEMM, 64x128 tile, BK=64, global_load_lds, 3 blk/CU ----------
__global__ __launch_bounds__(256, 3) void qkv_gemm(const ushort* __restrict__ xb,
    const ushort* __restrict__ Wt, ushort* __restrict__ qo,
    ushort* __restrict__ ko, ushort* __restrict__ vTo) {
  const int m0 = blockIdx.x * 64;
  const int mat = blockIdx.y;
  const ushort* Bsrc = Wt + (size_t)mat * H_ * E_;
  __shared__ ushort As[2][64 * 64];
  __shared__ ushort Bs[2][128 * 64];
  const int tid = threadIdx.x;
  const int wave = tid >> 6, lane = tid & 63;
  const int col = lane & 15, quad = lane >> 4;
  const int wr = wave >> 1, wc = wave & 1;

  f32x4 acc[2][4];
  #pragma unroll
  for (int i = 0; i < 2; i++)
    #pragma unroll
    for (int j = 0; j < 4; j++) acc[i][j] = (f32x4){0.f,0.f,0.f,0.f};

  const int srow = lane >> 3;               // 0..7
  const int gcol = ((lane & 7) ^ srow) * 8; // XOR-swizzled 16B unit source offset

  #define STAGE_QKV(it, bufi) do { \
    _Pragma("unroll") \
    for (int j = 0; j < 2; j++) { \
      int rbase = wave*16 + j*8; \
      GLLDS16(xb + (size_t)(m0 + rbase + srow) * E_ + (it)*64 + gcol, \
              &As[bufi][rbase * 64]); \
    } \
    _Pragma("unroll") \
    for (int j = 0; j < 4; j++) { \
      int rbase = wave*32 + j*8; \
      GLLDS16(Bsrc + (size_t)(rbase + srow) * E_ + (it)*64 + gcol, \
              &Bs[bufi][rbase * 64]); \
    } \
  } while (0)

  STAGE_QKV(0, 0);
  __syncthreads();

  for (int it = 0; it < 16; it++) {
    if (it < 15) STAGE_QKV(it + 1, (it + 1) & 1);
    const ushort* a = &As[it & 1][0];
    const ushort* bb = &Bs[it & 1][0];
    #pragma unroll
    for (int kc = 0; kc < 2; kc++) {
      bf16x8 af[2], bf[4];
      #pragma unroll
      for (int mi = 0; mi < 2; mi++) {
        int rr = wr*32 + mi*16 + col;
        af[mi] = *(const bf16x8*)(a + rr*64 + (((kc*4 + quad) ^ (col & 7)) * 8));
      }
      #pragma unroll
      for (int ni = 0; ni < 4; ni++) {
        int rr = wc*64 + ni*16 + col;
        bf[ni] = *(const bf16x8*)(bb + rr*64 + (((kc*4 + quad) ^ (col & 7)) * 8));
      }
      #pragma unroll
      for (int mi = 0; mi < 2; mi++)
        #pragma unroll
        for (int ni = 0; ni < 4; ni++)
          acc[mi][ni] = __builtin_amdgcn_mfma_f32_16x16x32_bf16(af[mi], bf[ni], acc[mi][ni], 0, 0, 0);
    }
    __syncthreads();
  }

  if (mat == 2) {
    int bb = m0 >> 12;
    int sbase = (m0 & 4095) + wr * 32;
    #pragma unroll
    for (int ni = 0; ni < 4; ni++) {
      int n = wc*64 + ni*16 + col;
      #pragma unroll
      for (int mi = 0; mi < 2; mi++) {
        int s = sbase + mi*16 + quad*4;
        ushort4 o;
        o.x = f2bf(acc[mi][ni][0]); o.y = f2bf(acc[mi][ni][1]);
        o.z = f2bf(acc[mi][ni][2]); o.w = f2bf(acc[mi][ni][3]);
        *(ushort4*)(vTo + ((size_t)(bb * H_ + n)) * S_ + s) = o;
      }
    }
  } else {
    ushort* dst = (mat == 0 ? qo : ko);
    #pragma unroll
    for (int ni = 0; ni < 4; ni++) {
      int n = wc*64 + ni*16 + col;
      #pragma unroll
      for (int mi = 0; mi < 2; mi++) {
        int row = m0 + wr*32 + mi*16 + quad*4;
        #pragma unroll
        for (int r = 0; r < 4; r++)
          dst[(size_t)(row + r) * H_ + n] = f2bf(acc[mi][ni][r]);
      }
    }
  }
}

// ---------- kernel 4: causal flash, split-K chunk=256, tile-pair WGs, bf16 partials ----------
// grid (c=16, y=32 reversed, b=4); valid iff 2c <= tp. 1088 valid WGs.
// NOTE: launch_bounds min-waves MUST be 2: (256,4) forces VGPR=64 -> 600MB spill
// (R7, 283us); (256,3) forces VGPR=84 -> 70MB spill (R8, 182us). (256,2) gives
// VGPR~108, zero spill (R6, 93us at chunk=512).
#define CHUNK_ 256
__global__ __launch_bounds__(256, 2) void flash_kernel(const ushort* __restrict__ q,
    const ushort* __restrict__ k, const ushort* __restrict__ vT,
    ushort* __restrict__ Opart, float* __restrict__ ml) {
  const float SL2E = 0.08838834764831845f * 1.44269504088896340736f;
  int c = blockIdx.x;
  int tp = 31 - (int)blockIdx.y;              // heavy pairs first
  int b = blockIdx.z;
  if (tp < 2 * c) return;
  int tA = tp * 2, tB = tA + 1;
  int nc = (tp >> 1) + 1;
  int base2 = tp + ((tp - 1) >> 1) * (tp >> 1);   // sum of nc(t) for t<tp
  int slotA = b * 544 + 2 * base2 + c;
  int slotB = slotA + nc;

  int wave = threadIdx.x >> 6, lane = threadIdx.x & 63;
  int col = lane & 15, quad = lane >> 4;
  int xa16 = ((lane ^ 16) << 2);
  int xa32 = ((lane ^ 32) << 2);
  int q0A = tA * 64 + wave * 16;
  int q0B = q0A + 64;
  const ushort* qb = q + (size_t)b * S_ * H_;
  const ushort* kbp = k + (size_t)b * S_ * H_;
  const ushort* vb = vT + (size_t)b * H_ * S_;

  __shared__ ushort kl[2][32 * 128];          // K block, XOR-swizzled 16B units
  __shared__ ushort plds[4][2][16 * 40];      // P per (wave, tile)
  ushort* pwA = &plds[wave][0][0];
  ushort* pwB = &plds[wave][1][0];

  bf16x8 qfA[4], qfB[4];
  {
    const ushort* qpA = qb + (size_t)(q0A + col) * H_ + quad * 8;
    const ushort* qpB = qb + (size_t)(q0B + col) * H_ + quad * 8;
    #pragma unroll
    for (int kc = 0; kc < 4; kc++) {
      qfA[kc] = *(const bf16x8*)(qpA + kc * 32);
      qfB[kc] = *(const bf16x8*)(qpB + kc * 32);
    }
  }

  f32x4 OA[8], OB[8];
  #pragma unroll
  for (int d = 0; d < 8; d++) { OA[d] = (f32x4){0.f,0.f,0.f,0.f}; OB[d] = (f32x4){0.f,0.f,0.f,0.f}; }
  float mA = -1e30f, lA = 0.f, mB = -1e30f, lB = 0.f;

  const int c0 = c * CHUNK_;
  const int kendWG = min(c0 + CHUNK_, tB * 64 + 64);
  const int nblk = (kendWG - c0 + 31) >> 5;
  const int qlimA = q0A + 15, qlimB = q0B + 15;

  const int sk0 = wave * 8 + (lane >> 4);
  const int sd = lane & 15;
  const int gu0 = (sd ^ (sk0 & 15)) * 8;
  const int gu1 = (sd ^ ((sk0 + 4) & 15)) * 8;
  ushort* ld0 = &kl[0][(sk0) * 128 + sd * 8];
  ushort* ld1 = &kl[0][(sk0 + 4) * 128 + sd * 8];
  const size_t lbuf = 32 * 128;

  const ushort* vbase = vb + (size_t)col * S_ + c0 + quad * 8;

  {
    const ushort* kp = kbp + (size_t)(c0 + sk0) * H_;
    uint4 a0 = *(const uint4*)(kp + gu0);
    uint4 a1 = *(const uint4*)(kp + 4 * H_ + gu1);
    *(uint4*)ld0 = a0;
    *(uint4*)ld1 = a1;
  }
  __syncthreads();

  for (int ib = 0; ib < nblk; ib++) {
    const int kb0 = c0 + ib * 32;
    if (ib + 1 < nblk) {
      const ushort* kp = kbp + (size_t)(kb0 + 32 + sk0) * H_;
      uint4 a0 = *(const uint4*)(kp + gu0);
      uint4 a1 = *(const uint4*)(kp + 4 * H_ + gu1);
      size_t off = ((ib + 1) & 1) * lbuf;
      *(uint4*)(ld0 + off) = a0;
      *(uint4*)(ld1 + off) = a1;
    }
    if (kb0 <= qlimB) {                       // wave-uniform
      const bool doA = (kb0 <= qlimA);
      bf16x8 vf[8];
      #pragma unroll
      for (int d = 0; d < 8; d++)
        vf[d] = *(const bf16x8*)(vbase + ib * 32 + (size_t)(d * 16) * S_);
      const ushort* kcur = &kl[ib & 1][0];
      bf16x8 kf0[4], kf1[4];
      #pragma unroll
      for (int kc = 0; kc < 4; kc++) {
        int u = quad + kc * 4;
        kf0[kc] = *(const bf16x8*)(kcur + col*128        + ((u ^ (col & 15)) * 8));
        kf1[kc] = *(const bf16x8*)(kcur + (16 + col)*128 + ((u ^ (col & 15)) * 8));
      }
      f32x4 sB0 = (f32x4){0.f,0.f,0.f,0.f}, sB1 = (f32x4){0.f,0.f,0.f,0.f};
      f32x4 sA0 = (f32x4){0.f,0.f,0.f,0.f}, sA1 = (f32x4){0.f,0.f,0.f,0.f};
      #pragma unroll
      for (int kc = 0; kc < 4; kc++) {
        sB0 = __builtin_amdgcn_mfma_f32_16x16x32_bf16(kf0[kc], qfB[kc], sB0, 0, 0, 0);
        sB1 = __builtin_amdgcn_mfma_f32_16x16x32_bf16(kf1[kc], qfB[kc], sB1, 0, 0, 0);
      }
      if (doA) {
        #pragma unroll
        for (int kc = 0; kc < 4; kc++) {
          sA0 = __builtin_amdgcn_mfma_f32_16x16x32_bf16(kf0[kc], qfA[kc], sA0, 0, 0, 0);
          sA1 = __builtin_amdgcn_mfma_f32_16x16x32_bf16(kf1[kc], qfA[kc], sA1, 0, 0, 0);
        }
      }
      // ---- tile B softmax ----
      {
        float s[8];
        #pragma unroll
        for (int r = 0; r < 4; r++) { s[r] = sB0[r]; s[4+r] = sB1[r]; }
        if (kb0 + 31 > q0B) {
          #pragma unroll
          for (int r = 0; r < 4; r++) {
            if (kb0 + quad*4 + r      > q0B + col) s[r]   = -1e30f;
            if (kb0 + 16 + quad*4 + r > q0B + col) s[4+r] = -1e30f;
          }
        }
        float cm = s[0];
        #pragma unroll
        for (int j = 1; j < 8; j++) cm = fmaxf(cm, s[j]);
        cm = fmaxf(cm, bpermf(xa16, cm));
        cm = fmaxf(cm, bpermf(xa32, cm));
        float mn = fmaxf(mB, cm);
        float alpha = exp2f((mB - mn) * SL2E);
        mB = mn;
        float p[8], rs = 0.f;
        #pragma unroll
        for (int j = 0; j < 8; j++) { p[j] = exp2f((s[j] - mn) * SL2E); rs += p[j]; }
        rs += bpermf(xa16, rs);
        rs += bpermf(xa32, rs);
        lB = lB * alpha + rs;
        #pragma unroll
        for (int d = 0; d < 8; d++) OB[d] *= alpha;
        unsigned* pq = (unsigned*)(pwB + col * 40);
        pq[quad*2]     = (unsigned)f2bf(p[0]) | ((unsigned)f2bf(p[1]) << 16);
        pq[quad*2+1]   = (unsigned)f2bf(p[2]) | ((unsigned)f2bf(p[3]) << 16);
        pq[8+quad*2]   = (unsigned)f2bf(p[4]) | ((unsigned)f2bf(p[5]) << 16);
        pq[8+quad*2+1] = (unsigned)f2bf(p[6]) | ((unsigned)f2bf(p[7]) << 16);
      }
      // ---- tile A softmax ----
      if (doA) {
        float s[8];
        #pragma unroll
        for (int r = 0; r < 4; r++) { s[r] = sA0[r]; s[4+r] = sA1[r]; }
        if (kb0 + 31 > q0A) {
          #pragma unroll
          for (int r = 0; r < 4; r++) {
            if (kb0 + quad*4 + r      > q0A + col) s[r]   = -1e30f;
            if (kb0 + 16 + quad*4 + r > q0A + col) s[4+r] = -1e30f;
          }
        }
        float cm = s[0];
        #pragma unroll
        for (int j = 1; j < 8; j++) cm = fmaxf(cm, s[j]);
        cm = fmaxf(cm, bpermf(xa16, cm));
        cm = fmaxf(cm, bpermf(xa32, cm));
        float mn = fmaxf(mA, cm);
        float alpha = exp2f((mA - mn) * SL2E);
        mA = mn;
        float p[8], rs = 0.f;
        #pragma unroll
        for (int j = 0; j < 8; j++) { p[j] = exp2f((s[j] - mn) * SL2E); rs += p[j]; }
        rs += bpermf(xa16, rs);
        rs += bpermf(xa32, rs);
        lA = lA * alpha + rs;
        #pragma unroll
        for (int d = 0; d < 8; d++) OA[d] *= alpha;
        unsigned* pq = (unsigned*)(pwA + col * 40);
        pq[quad*2]     = (unsigned)f2bf(p[0]) | ((unsigned)f2bf(p[1]) << 16);
        pq[quad*2+1]   = (unsigned)f2bf(p[2]) | ((unsigned)f2bf(p[3]) << 16);
        pq[8+quad*2]   = (unsigned)f2bf(p[4]) | ((unsigned)f2bf(p[5]) << 16);
        pq[8+quad*2+1] = (unsigned)f2bf(p[6]) | ((unsigned)f2bf(p[7]) << 16);
      }
      // ---- PV for both ----
      {
        bf16x8 pfB = *(const bf16x8*)(pwB + col * 40 + quad * 8);
        #pragma unroll
        for (int d = 0; d < 8; d++)
          OB[d] = __builtin_amdgcn_mfma_f32_16x16x32_bf16(vf[d], pfB, OB[d], 0, 0, 0);
        if (doA) {
          bf16x8 pfA = *(const bf16x8*)(pwA + col * 40 + quad * 8);
          #pragma unroll
          for (int d = 0; d < 8; d++)
            OA[d] = __builtin_amdgcn_mfma_f32_16x16x32_bf16(vf[d], pfA, OA[d], 0, 0, 0);
        }
      }
    }
    __syncthreads();
  }

  // bf16 partials
  ushort* OpA = Opart + (size_t)slotA * 8192 + (size_t)(wave*16 + col) * 128 + quad * 4;
  ushort* OpB = Opart + (size_t)slotB * 8192 + (size_t)(wave*16 + col) * 128 + quad * 4;
  #pragma unroll
  for (int d = 0; d < 8; d++) {
    ushort4 oa, ob;
    oa.x=f2bf(OA[d][0]); oa.y=f2bf(OA[d][1]); oa.z=f2bf(OA[d][2]); oa.w=f2bf(OA[d][3]);
    ob.x=f2bf(OB[d][0]); ob.y=f2bf(OB[d][1]); ob.z=f2bf(OB[d][2]); ob.w=f2bf(OB[d][3]);
    *(ushort4*)(OpA + d * 16) = oa;
    *(ushort4*)(OpB + d * 16) = ob;
  }
  if (quad == 0) {
    *(float2*)(ml + (size_t)slotA * 128 + (size_t)(wave*16 + col) * 2) = make_float2(mA, lA);
    *(float2*)(ml + (size_t)slotB * 128 + (size_t)(wave*16 + col) * 2) = make_float2(mB, lB);
  }
}

// ---------- kernel 5: combine split-K partials (bf16 partials, array-free) ----------
__global__ __launch_bounds__(256) void combine_kernel(const ushort* __restrict__ Opart,
    const float* __restrict__ ml, float* __restrict__ out) {
  const float SL2E = 0.08838834764831845f * 1.44269504088896340736f;
  int tile = blockIdx.x, b = blockIdx.y;
  int tp = tile >> 1;
  int nc = (tp >> 1) + 1;
  int base2 = tp + ((tp - 1) >> 1) * (tp >> 1);
  int base = b * 544 + 2 * base2 + (tile & 1) * nc;
  int tid = threadIdx.x;
  int row = tid >> 2;
  int cs = (tid & 3) * 4;
  // pass 1: global max (no arrays -> no scratch)
  float mstar = -1e30f;
  for (int ci = 0; ci < nc; ci++)
    mstar = fmaxf(mstar, ml[(size_t)(base + ci) * 128 + row * 2]);
  // pass 2: accumulate with on-the-fly weights
  float denom = 0.f;
  f32x4 acc[8];
  #pragma unroll
  for (int i = 0; i < 8; i++) acc[i] = (f32x4){0.f,0.f,0.f,0.f};
  for (int ci = 0; ci < nc; ci++) {
    float2 ml2 = *(const float2*)(ml + (size_t)(base + ci) * 128 + row * 2);
    float w = exp2f((ml2.x - mstar) * SL2E);
    denom += w * ml2.y;
    const ushort* Op = Opart + (size_t)(base + ci) * 8192 + row * 128;
    #pragma unroll
    for (int i = 0; i < 8; i++) {
      ushort4 u = *(const ushort4*)(Op + cs + i * 16);
      acc[i][0] += w * bf2f(u.x);
      acc[i][1] += w * bf2f(u.y);
      acc[i][2] += w * bf2f(u.z);
      acc[i][3] += w * bf2f(u.w);
    }
  }
  float inv = 1.f / denom;
  float* o = out + ((size_t)(b * S_) + tile * 64 + row) * H_;
  #pragma unroll
  for (int i = 0; i < 8; i++) {
    f32x4 v = acc[i] * inv;
    *(f32x4*)(o + cs + i * 16) = v;
  }
}

extern "C" void kernel_launch(void* const* d_in, const int* in_sizes, int n_in,
                              void* d_out, int out_size, void* d_ws, size_t ws_size,
                              hipStream_t stream) {
  (void)in_sizes; (void)n_in; (void)out_size; (void)ws_size;
  const float* x  = (const float*)d_in[0];
  const float* Wq = (const float*)d_in[1];
  const float* Wk = (const float*)d_in[2];
  const float* Wv = (const float*)d_in[3];
  float* out = (float*)d_out;
  char* ws = (char*)d_ws;
  ushort* Wt = (ushort*)ws;                                        // 768 KB
  ushort* qb = (ushort*)(ws + 786432);                             // 4 MB each
  ushort* kb = qb + (size_t)M_ * H_;
  ushort* vT = kb + (size_t)M_ * H_;
  ushort* Opart = (ushort*)(ws + 786432 + 3 * (size_t)M_ * H_ * 2); // 2176*16KB = 35.7MB
  float* ml = (float*)(Opart + (size_t)2176 * 8192);               // 2176*512B
  ushort* xbuf = Opart;            // alias: xbuf dead before flash writes Opart

  hipLaunchKernelGGL(wt_kernel,   dim3(384), dim3(256), 0, stream, Wq, Wk, Wv, Wt);
  hipLaunchKernelGGL(xb_kernel,   dim3(8192), dim3(256), 0, stream, x, xbuf);
  hipLaunchKernelGGL(qkv_gemm,    dim3(256, 3), dim3(256), 0, stream, xbuf, Wt, qb, kb, vT);
  hipLaunchKernelGGL(flash_kernel,dim3(16, 32, 4), dim3(256), 0, stream, qb, kb, vT, Opart, ml);
  hipLaunchKernelGGL(combine_kernel, dim3(64, 4), dim3(256), 0, stream, Opart, ml, out);
}